// Round 6
// baseline (4954.475 us; speedup 1.0000x reference)
//
#include <hip/hip_runtime.h>

#define B_ 64
#define T_ 4096
#define D_ 128
#define H_ 256

// Barrier that waits only on LDS ops (lgkmcnt), NOT on in-flight global
// loads/stores (vmcnt). __syncthreads() would drain vmcnt(0) every step,
// serializing the xp prefetch (HBM ~900 cyc) and h store retire into the
// critical path. Our per-step cross-thread hazards are LDS-only.
__device__ __forceinline__ void barrier_lgkm() {
    asm volatile("s_waitcnt lgkmcnt(0)" ::: "memory");
    __builtin_amdgcn_s_barrier();
    asm volatile("" ::: "memory");
}

// ---------------------------------------------------------------------------
// Kernel A: xp = x @ Wx + bx, written into `out`. (unchanged this round)
// ---------------------------------------------------------------------------
__global__ __launch_bounds__(1024) void xp_kernel(const float* __restrict__ x,
                                                  const float* __restrict__ Wx,
                                                  const float* __restrict__ bx,
                                                  float* __restrict__ out) {
    __shared__ float xs[64 * D_];
    const int tid = threadIdx.x;
    const int j = tid & 255;
    const int q = tid >> 8;                    // 0..3 -> rows 16q..16q+15
    const long row0 = (long)blockIdx.x * 64;

    const float4* xg = (const float4*)(x + row0 * D_);
    float4* xs4 = (float4*)xs;
    for (int i = tid; i < (64 * D_) / 4; i += 1024) xs4[i] = xg[i];
    __syncthreads();

    float acc[16];
#pragma unroll
    for (int r = 0; r < 16; ++r) acc[r] = 0.f;

    for (int k0 = 0; k0 < D_; k0 += 4) {
        const float w0 = Wx[(k0 + 0) * H_ + j];
        const float w1 = Wx[(k0 + 1) * H_ + j];
        const float w2 = Wx[(k0 + 2) * H_ + j];
        const float w3 = Wx[(k0 + 3) * H_ + j];
#pragma unroll
        for (int r = 0; r < 16; ++r) {
            const float4 xv = *(const float4*)(&xs[(q * 16 + r) * D_ + k0]);  // broadcast
            acc[r] += xv.x * w0 + xv.y * w1 + xv.z * w2 + xv.w * w3;
        }
    }

    const float bj = bx[j];
#pragma unroll
    for (int r = 0; r < 16; ++r) {
        out[(row0 + q * 16 + r) * H_ + j] = acc[r] + bj;   // coalesced across j
    }
}

// ---------------------------------------------------------------------------
// Kernel B: per-batch recurrence h_t = tanh(xp_t + h_{t-1} @ Wh + bh).
// grid = 64 blocks, 512 threads (8 waves, 2/SIMD).
//
// ONE barrier per step (was 2 + a partial-reduce LDS round trip). No
// cross-wave reduction: wave w owns outputs [32w,32w+32); a LANE PAIR owns
// one output (even lane: k in [0,128), odd lane: k in [128,256)); halves
// combine with a single in-register __shfl_xor(p,1) — no LDS, no barrier.
// Each lane holds 128 Wh values in VGPRs (float4 wreg[32]).
// hs double-buffered: step t reads hs[t&1], writes hs[(t+1)&1]; the single
// lgkm barrier closes both hazards (reads(t) drain via lgkmcnt before the
// barrier; writes(t+1) happen after it).
// Even lanes: + xp + bias, fast tanh, hs write (32 stride-1 b32 = clean)
// + coalesced 128B/wave global store. xp t+2 prefetch stays in flight.
// ---------------------------------------------------------------------------
__global__ __launch_bounds__(512, 2) void rnn_kernel(const float* __restrict__ Wh,
                                                     const float* __restrict__ bh,
                                                     float* __restrict__ out) {
    const int b = blockIdx.x;
    const int tid = threadIdx.x;               // 0..511
    const int lane = tid & 63;
    const int w = tid >> 6;                    // wave 0..7
    const int half = lane & 1;                 // k-half owner
    const int j = (w << 5) + (lane >> 1);      // output index 0..255
    const int kbase = half << 7;               // 0 or 128

    __shared__ float hs[2][H_];

    // wreg[c] = Wh[kbase+4c .. kbase+4c+3][j]  (128 VGPRs)
    float4 wreg[32];
#pragma unroll
    for (int c = 0; c < 32; ++c) {
        wreg[c].x = Wh[(kbase + 4 * c + 0) * H_ + j];
        wreg[c].y = Wh[(kbase + 4 * c + 1) * H_ + j];
        wreg[c].z = Wh[(kbase + 4 * c + 2) * H_ + j];
        wreg[c].w = Wh[(kbase + 4 * c + 3) * H_ + j];
    }
    const float bhj = bh[j];

    ((float*)hs)[tid] = 0.f;                   // 512 threads zero both buffers
    __syncthreads();                           // once; vmcnt drain here is fine

    float* obase = out + (long)b * T_ * H_;
    float xp0 = 0.f, xp1 = 0.f;
    if (half == 0) {
        xp0 = obase[j];                        // xp[b][0][j]
        xp1 = obase[H_ + j];                   // xp[b][1][j]
    }

#pragma unroll 2
    for (int t = 0; t < T_; ++t) {
        const float* hb = hs[t & 1];

        // prefetch xp for t+2; vmcnt wait lands ~1 full step later
        float xp2 = 0.f;
        if (half == 0 && t + 2 < T_) xp2 = obase[(long)(t + 2) * H_ + j];

        // 32 broadcast b128 reads (2 addr classes/instr = free alias) + 128 FMAs
        float a0 = 0.f, a1 = 0.f, a2 = 0.f, a3 = 0.f;
#pragma unroll
        for (int c = 0; c < 32; ++c) {
            const float4 hv = *(const float4*)(&hb[kbase + 4 * c]);
            a0 += hv.x * wreg[c].x;
            a1 += hv.y * wreg[c].y;
            a2 += hv.z * wreg[c].z;
            a3 += hv.w * wreg[c].w;
        }
        float p = (a0 + a1) + (a2 + a3);
        p += __shfl_xor(p, 1, 64);             // combine k-halves within lane pair

        if (half == 0) {
            float sum = p + xp0 + bhj;
            // branchless tanh: clamp, e = exp(2s), (e-1)/(e+1)
            sum = fminf(15.f, fmaxf(-15.f, sum));
            const float e = __expf(2.f * sum);
            const float hn = __fdividef(e - 1.f, e + 1.f);
            hs[(t + 1) & 1][j] = hn;
            obase[(long)t * H_ + j] = hn;      // fire-and-forget store
            xp0 = xp1;
            xp1 = xp2;
        }
        barrier_lgkm();                        // the ONLY per-step barrier
    }
}

extern "C" void kernel_launch(void* const* d_in, const int* in_sizes, int n_in,
                              void* d_out, int out_size, void* d_ws, size_t ws_size,
                              hipStream_t stream) {
    const float* x  = (const float*)d_in[0];
    const float* Wx = (const float*)d_in[1];
    const float* bx = (const float*)d_in[2];
    const float* Wh = (const float*)d_in[3];
    const float* bh = (const float*)d_in[4];
    float* out = (float*)d_out;

    xp_kernel<<<(B_ * T_) / 64, 1024, 0, stream>>>(x, Wx, bx, out);
    rnn_kernel<<<B_, 512, 0, stream>>>(Wh, bh, out);
}